// Round 20
// baseline (159.214 us; speedup 1.0000x reference)
//
#include <hip/hip_runtime.h>
#include <hip/hip_bf16.h>

// R20: attn = R9's 32q-per-wave shape (fits 128-reg HW granule -> 4 waves/
// SIMD) + sched_barrier(0) pins after each K/V prefetch issue to stop the
// allocator sinking loads to their uses (R9's failure: squeezed to 64 VGPR,
// serialized, 128us). Occupancy model: VGPR_Count excludes the O-accumulator;
// R16's 104+64=168 rounds to the 256 granule -> 2 waves/SIMD forever. The
// 32q shape totals ~112 -> 128 granule -> 4 waves/SIMD at grid 512.
// prep/proj unchanged from R16 (Q pre-scaled by log2e/8; masks folded).

typedef short  s16x8 __attribute__((ext_vector_type(8)));
typedef short  s16x4 __attribute__((ext_vector_type(4)));
typedef float  f32x4 __attribute__((ext_vector_type(4)));
typedef float  f32x16 __attribute__((ext_vector_type(16)));
typedef unsigned int u32;
typedef unsigned int u32x4 __attribute__((ext_vector_type(4)));

__device__ __forceinline__ unsigned short f2bf(float x) {
    return __builtin_bit_cast(unsigned short, __float2bfloat16(x));
}
__device__ __forceinline__ void gload16(const void* g, void* lds) {
    __builtin_amdgcn_global_load_lds(
        (const __attribute__((address_space(1))) unsigned int*)g,
        (__attribute__((address_space(3))) unsigned int*)lds, 16, 0, 0);
}
__device__ __forceinline__ u32 cvtpk(float lo, float hi) {
    u32 r;
    asm("v_cvt_pk_bf16_f32 %0, %1, %2" : "=v"(r) : "v"(lo), "v"(hi));
    return r;
}

// ---------------- prep: cast q,k; transpose/cast W; count masked keys ------
__global__ __launch_bounds__(256) void prep(
    const float* __restrict__ q, const float* __restrict__ k,
    const float* __restrict__ Wq, const float* __restrict__ Wk,
    const float* __restrict__ Wv, const int* __restrict__ mask,
    unsigned short* __restrict__ qbf, unsigned short* __restrict__ kbf,
    unsigned short* __restrict__ wtq, unsigned short* __restrict__ wtk,
    unsigned short* __restrict__ wtv, int* __restrict__ cntb)
{
    __shared__ float T[64][65];
    const int bid = blockIdx.x;
    const int tid = threadIdx.x;
    if (bid < 3072) {
        const float* src = bid < 1024 ? q : k;
        unsigned short* dst = bid < 1024 ? qbf : kbf;
        int i = (bid < 1024 ? bid : bid - 1024) * 256 + tid;
        float4 a = reinterpret_cast<const float4*>(src)[2 * i];
        float4 b = reinterpret_cast<const float4*>(src)[2 * i + 1];
        s16x8 o;
        o[0] = (short)f2bf(a.x); o[1] = (short)f2bf(a.y);
        o[2] = (short)f2bf(a.z); o[3] = (short)f2bf(a.w);
        o[4] = (short)f2bf(b.x); o[5] = (short)f2bf(b.y);
        o[6] = (short)f2bf(b.z); o[7] = (short)f2bf(b.w);
        reinterpret_cast<s16x8*>(dst)[i] = o;
    } else if (bid < 3264) {
        int t = bid - 3072;
        int z = t >> 6;
        int tt = t & 63;
        const float* W = z == 0 ? Wq : z == 1 ? Wk : Wv;
        unsigned short* D = z == 0 ? wtq : z == 1 ? wtk : wtv;
        const int k0 = (tt >> 3) * 64, n0 = (tt & 7) * 64;
        const int r = tid >> 2, cq = tid & 3;
        #pragma unroll
        for (int p = 0; p < 4; ++p) {
            int c = (cq + 4 * p) * 4;
            float4 v = *reinterpret_cast<const float4*>(
                &W[(size_t)(k0 + r) * 512 + n0 + c]);
            T[c + 0][r] = v.x; T[c + 1][r] = v.y;
            T[c + 2][r] = v.z; T[c + 3][r] = v.w;
        }
        __syncthreads();
        #pragma unroll
        for (int p = 0; p < 4; ++p) {
            int kc = (cq + 4 * p) * 4;
            s16x4 o;
            o[0] = (short)f2bf(T[r][kc + 0]);
            o[1] = (short)f2bf(T[r][kc + 1]);
            o[2] = (short)f2bf(T[r][kc + 2]);
            o[3] = (short)f2bf(T[r][kc + 3]);
            *reinterpret_cast<s16x4*>(&D[(size_t)(n0 + r) * 512 + k0 + kc]) = o;
        }
    } else {
        // blocks 3264/3265: per-batch masked-key count (deterministic)
        __shared__ int red[4];
        int b = bid - 3264;
        int base = b * 4096 + tid * 16;
        int s = 0;
        #pragma unroll
        for (int p = 0; p < 4; ++p) {
            int4 m = *reinterpret_cast<const int4*>(&mask[base + 4 * p]);
            s += m.x + m.y + m.z + m.w;
        }
        #pragma unroll
        for (int off = 1; off < 64; off <<= 1)
            s += __shfl_xor(s, off);
        if ((tid & 63) == 0) red[tid >> 6] = s;
        __syncthreads();
        if (tid == 0)
            cntb[b] = 4096 - (red[0] + red[1] + red[2] + red[3]);
    }
}

// ---------------- fused 3-way projection GEMM, bf16 MFMA, 2-phase ----------
// mflag: 0 = Q (scale by log2e/8), 1 = K (zero masked rows), 2 = V^T.
__global__ __launch_bounds__(256) void proj3(
    const unsigned short* __restrict__ qbf, const unsigned short* __restrict__ kbf,
    const unsigned short* __restrict__ wtq, const unsigned short* __restrict__ wtk,
    const unsigned short* __restrict__ wtv,
    const float* __restrict__ bq, const float* __restrict__ bk,
    const float* __restrict__ bv, const int* __restrict__ mask,
    unsigned short* __restrict__ qh, unsigned short* __restrict__ kh,
    unsigned short* __restrict__ vt)
{
    __shared__ unsigned short As[2][128 * 64];
    __shared__ unsigned short Bs[2][64 * 64];

    const int tid  = threadIdx.x;
    const int wv   = tid >> 6;
    const int lane = tid & 63;
    const int g    = lane >> 4;
    const int ln   = lane & 15;
    const int swz  = (ln & 7) << 3;

    const int id = blockIdx.x;
    const unsigned short *A, *Wt;
    const float* bias;
    unsigned short* dst;
    int S, trans, nb, mb, mflag;
    if (id < 256)      { A = qbf; Wt = wtq; bias = bq; dst = qh; S = 2048; trans = 0; mflag = 0; nb = id & 7;         mb = id >> 3; }
    else if (id < 768) { A = kbf; Wt = wtk; bias = bk; dst = kh; S = 4096; trans = 0; mflag = 1; nb = (id - 256) & 7; mb = (id - 256) >> 3; }
    else               { A = kbf; Wt = wtv; bias = bv; dst = vt; S = 4096; trans = 1; mflag = 2; nb = (id - 768) & 7; mb = (id - 768) >> 3; }
    const int m0 = mb * 128, n0 = nb * 64;
    const float scl = (mflag == 0) ? 0.18033688011112042f : 1.f;

    f32x4 acc[4][2];
    #pragma unroll
    for (int i = 0; i < 4; ++i)
        #pragma unroll
        for (int j = 0; j < 2; ++j) acc[i][j] = (f32x4)0.f;

    auto stage = [&](int bufn, int k0) {
        #pragma unroll
        for (int p = 0; p < 4; ++p) {
            int slot = p * 256 + tid;
            int row = slot >> 3, cb = slot & 7;
            int cbp = cb ^ (row & 7);
            gload16(&A[(size_t)(m0 + row) * 512 + k0 + cbp * 8], &As[bufn][slot * 8]);
        }
        #pragma unroll
        for (int p = 0; p < 2; ++p) {
            int slot = p * 256 + tid;
            int row = slot >> 3, cb = slot & 7;
            int cbp = cb ^ (row & 7);
            gload16(&Wt[(size_t)(n0 + row) * 512 + k0 + cbp * 8], &Bs[bufn][slot * 8]);
        }
    };

    stage(0, 0);
    __syncthreads();
    int buf = 0;
    for (int kk = 0; kk < 8; ++kk) {
        if (kk < 7) stage(buf ^ 1, (kk + 1) * 64);
        #pragma unroll
        for (int ks = 0; ks < 2; ++ks) {
            s16x8 fa[2], fb[4];
            #pragma unroll
            for (int mi = 0; mi < 2; ++mi)
                fa[mi] = *reinterpret_cast<const s16x8*>(
                    &As[buf][((wv * 32 + 16 * mi + ln) * 64 + ks * 32 + g * 8) ^ swz]);
            #pragma unroll
            for (int nj = 0; nj < 4; ++nj)
                fb[nj] = *reinterpret_cast<const s16x8*>(
                    &Bs[buf][((16 * nj + ln) * 64 + ks * 32 + g * 8) ^ swz]);
            if (!trans) {
                #pragma unroll
                for (int mi = 0; mi < 2; ++mi)
                    #pragma unroll
                    for (int nj = 0; nj < 4; ++nj)
                        acc[nj][mi] = __builtin_amdgcn_mfma_f32_16x16x32_bf16(
                            fa[mi], fb[nj], acc[nj][mi], 0, 0, 0);
            } else {
                #pragma unroll
                for (int nj = 0; nj < 4; ++nj)
                    #pragma unroll
                    for (int mi = 0; mi < 2; ++mi)
                        acc[nj][mi] = __builtin_amdgcn_mfma_f32_16x16x32_bf16(
                            fb[nj], fa[mi], acc[nj][mi], 0, 0, 0);
            }
        }
        __syncthreads();
        buf ^= 1;
    }

    const int h    = nb;
    const int bidx = m0 / S;
    const int s0   = m0 - bidx * S;

    if (!trans) {
        float bvv[4];
        #pragma unroll
        for (int nj = 0; nj < 4; ++nj) bvv[nj] = bias[n0 + 16 * nj + ln];
        unsigned short* base = dst + (size_t)(bidx * 8 + h) * S * 64;
        #pragma unroll
        for (int mi = 0; mi < 2; ++mi)
            #pragma unroll
            for (int r = 0; r < 4; ++r) {
                int s = s0 + wv * 32 + 16 * mi + 4 * g + r;
                float fm = (mflag == 1) ? (float)mask[bidx * 4096 + s] : 1.f;
                float fs = fm * scl;
                #pragma unroll
                for (int nj = 0; nj < 4; ++nj)
                    base[(size_t)s * 64 + 16 * nj + ln] =
                        f2bf((acc[nj][mi][r] + bvv[nj]) * fs);
            }
    } else {
        float fmc[2];
        #pragma unroll
        for (int mi = 0; mi < 2; ++mi)
            fmc[mi] = (float)mask[bidx * 4096 + s0 + wv * 32 + 16 * mi + ln];
        unsigned short* base = dst + (size_t)(bidx * 8 + h) * 64 * (size_t)S;
        #pragma unroll
        for (int nj = 0; nj < 4; ++nj)
            #pragma unroll
            for (int r = 0; r < 4; ++r) {
                int w = 16 * nj + 4 * g + r;
                float bw = bias[n0 + w];
                #pragma unroll
                for (int mi = 0; mi < 2; ++mi)
                    base[(size_t)w * S + s0 + wv * 32 + 16 * mi + ln] =
                        f2bf((acc[nj][mi][r] + bw) * fmc[mi]);
            }
    }
}

// -------- attention: 32q x 32k per wave, sched_barrier-pinned prefetch -----
__global__ __launch_bounds__(512) void attn14(
    const unsigned short* __restrict__ qh,  // [B,8,2048,64] bf16 (pre-scaled)
    const unsigned short* __restrict__ kh,  // [B,8,4096,64] bf16 (masked rows 0)
    const unsigned short* __restrict__ vt,  // [B,8,64,4096] bf16 (masked cols 0)
    const int* __restrict__ cntb,           // [B] masked-key counts
    float* __restrict__ out)                // [B,2048,512]
{
    __shared__ float Ored[2][4][32][36];    // [qg][kq][q32][w32+pad]
    __shared__ float lw[2][4][32];          // [qg][kq][q32]

    const int tid  = threadIdx.x;
    const int wid  = tid >> 6;
    const int kq   = wid & 3;
    const int qg   = wid >> 2;
    const int lane = tid & 63;
    const int l31  = lane & 31;
    const int h32  = lane >> 5;

    const int id  = blockIdx.x;
    const int xcd = id & 7;
    const int j   = id >> 3;               // 0..63
    const int bh  = xcd * 2 + (j >> 5);
    const int qt  = j & 31;                // 64-row q tile
    const int b   = bh >> 3;
    const int hh  = bh & 7;

    const unsigned short* Kp = kh + (size_t)bh * 4096 * 64
                               + (size_t)(kq * 32 + l31) * 64 + h32 * 8;
    const unsigned short* Vp0 = vt + (size_t)bh * 64 * 4096
                               + (size_t)l31 * 4096 + kq * 32 + h32 * 8;

    s16x8 Qf[4];
    {
        const unsigned short* Qb = qh + ((size_t)bh * 2048 + qt * 64 + qg * 32) * 64;
        #pragma unroll
        for (int ks = 0; ks < 4; ++ks)
            Qf[ks] = *reinterpret_cast<const s16x8*>(
                &Qb[(size_t)l31 * 64 + ks * 16 + h32 * 8]);
    }

    f32x16 O[2];
    O[0] = (f32x16)0.f; O[1] = (f32x16)0.f;
    float l_acc = 0.f;

    s16x8 kf[4], vf[4];

    auto loadK = [&](int t) {
        #pragma unroll
        for (int ks = 0; ks < 4; ++ks)
            kf[ks] = *reinterpret_cast<const s16x8*>(Kp + (size_t)t * 8192 + ks * 16);
    };
    auto loadV = [&](int t) {
        #pragma unroll
        for (int wt = 0; wt < 2; ++wt)
            #pragma unroll
            for (int t2 = 0; t2 < 2; ++t2)
                vf[wt * 2 + t2] = *reinterpret_cast<const s16x8*>(
                    Vp0 + (size_t)wt * 32 * 4096 + t * 128 + t2 * 16);
    };

    loadK(0); loadV(0);

    for (int t = 0; t < 32; ++t) {
        // ---- QK^T: S^T[32 keys][32 q] (S pre-scaled via Q) -------------
        f32x16 S = (f32x16)0.f;
        __builtin_amdgcn_s_setprio(1);
        #pragma unroll
        for (int ks = 0; ks < 4; ++ks)
            S = __builtin_amdgcn_mfma_f32_32x32x16_bf16(kf[ks], Qf[ks], S, 0, 0, 0);
        __builtin_amdgcn_s_setprio(0);
        if (t < 31) loadK(t + 1);
        // pin: loadK stays issued HERE; latency covered by SM+PV below.
        __builtin_amdgcn_sched_barrier(0);

        // ---- no-max softmax: pp = exp2(S) ------------------------------
        float pp[16];
        #pragma unroll
        for (int r = 0; r < 16; ++r)
            pp[r] = exp2f(S[r]);
        l_acc += (((pp[0] + pp[1]) + (pp[2] + pp[3]))
                + ((pp[4] + pp[5]) + (pp[6] + pp[7])))
               + (((pp[8] + pp[9]) + (pp[10] + pp[11]))
                + ((pp[12] + pp[13]) + (pp[14] + pp[15])));
        u32 W[8];
        #pragma unroll
        for (int c = 0; c < 4; ++c) {
            W[2 * c + 0] = cvtpk(pp[4 * c + 0], pp[4 * c + 1]);
            W[2 * c + 1] = cvtpk(pp[4 * c + 2], pp[4 * c + 3]);
        }
        asm("v_permlane32_swap_b32 %0, %1" : "+v"(W[0]), "+v"(W[2]));
        asm("v_permlane32_swap_b32 %0, %1" : "+v"(W[1]), "+v"(W[3]));
        asm("v_permlane32_swap_b32 %0, %1" : "+v"(W[4]), "+v"(W[6]));
        asm("v_permlane32_swap_b32 %0, %1" : "+v"(W[5]), "+v"(W[7]));
        s16x8 pa[2];
        {
            u32x4 lo, hi;
            lo[0] = W[0]; lo[1] = W[1]; lo[2] = W[2]; lo[3] = W[3];
            hi[0] = W[4]; hi[1] = W[5]; hi[2] = W[6]; hi[3] = W[7];
            pa[0] = __builtin_bit_cast(s16x8, lo);
            pa[1] = __builtin_bit_cast(s16x8, hi);
        }

        // ---- PV: O[q][w] += P x V --------------------------------------
        __builtin_amdgcn_s_setprio(1);
        #pragma unroll
        for (int wt = 0; wt < 2; ++wt)
            #pragma unroll
            for (int t2 = 0; t2 < 2; ++t2)
                O[wt] = __builtin_amdgcn_mfma_f32_32x32x16_bf16(
                    pa[t2], vf[wt * 2 + t2], O[wt], 0, 0, 0);
        __builtin_amdgcn_s_setprio(0);
        if (t < 31) loadV(t + 1);
        // pin: loadV stays issued HERE; latency covered by next QK+SM.
        __builtin_amdgcn_sched_barrier(0);
    }

    // ---- l reduction: h32 pair then cross-wave via LDS ------------------
    float ls = l_acc + __shfl_xor(l_acc, 32);
    if (lane < 32) lw[qg][kq][l31] = ls;

    // ---- O reduction across the 4 kq waves ------------------------------
    const float cnt = (float)cntb[b];
    const int grp = tid >> 8;          // q-group (0/1)
    const int tt  = tid & 255;
    const int qr  = tt >> 3;
    const int w8  = (tt & 7) * 4;
    #pragma unroll
    for (int wt = 0; wt < 2; ++wt) {
        __syncthreads();
        #pragma unroll
        for (int r = 0; r < 16; ++r)
            Ored[qg][kq][(r & 3) + 8 * (r >> 2) + 4 * h32][l31] = O[wt][r];
        __syncthreads();
        float4 s0 = *reinterpret_cast<const float4*>(&Ored[grp][0][qr][w8]);
        float4 s1 = *reinterpret_cast<const float4*>(&Ored[grp][1][qr][w8]);
        float4 s2 = *reinterpret_cast<const float4*>(&Ored[grp][2][qr][w8]);
        float4 s3 = *reinterpret_cast<const float4*>(&Ored[grp][3][qr][w8]);
        float l = (lw[grp][0][qr] + lw[grp][1][qr]
                 + lw[grp][2][qr] + lw[grp][3][qr]) - cnt;
        float inv = 1.f / l;
        int qglob = qt * 64 + grp * 32 + qr;
        float4 o;
        o.x = (s0.x + s1.x + s2.x + s3.x) * inv;
        o.y = (s0.y + s1.y + s2.y + s3.y) * inv;
        o.z = (s0.z + s1.z + s2.z + s3.z) * inv;
        o.w = (s0.w + s1.w + s2.w + s3.w) * inv;
        *reinterpret_cast<float4*>(
            &out[((size_t)b * 2048 + qglob) * 512 + hh * 64 + wt * 32 + w8]) = o;
    }
}

extern "C" void kernel_launch(void* const* d_in, const int* in_sizes, int n_in,
                              void* d_out, int out_size, void* d_ws, size_t ws_size,
                              hipStream_t stream)
{
    const float* q    = (const float*)d_in[0];
    const float* k    = (const float*)d_in[1];
    const int*   mask = (const int*)  d_in[2];
    const float* Wq   = (const float*)d_in[3];
    const float* bq   = (const float*)d_in[4];
    const float* Wk   = (const float*)d_in[5];
    const float* bk   = (const float*)d_in[6];
    const float* Wv   = (const float*)d_in[7];
    const float* bv   = (const float*)d_in[8];
    float* out = (float*)d_out;

    // no aliasing: every buffer has a private range (total ~33.5MB)
    unsigned short* p = (unsigned short*)d_ws;
    unsigned short* qh  = p; p += (size_t)2 * 8 * 2048 * 64;   // 4MB
    unsigned short* kh  = p; p += (size_t)2 * 8 * 4096 * 64;   // 8MB
    unsigned short* vt  = p; p += (size_t)2 * 8 * 4096 * 64;   // 8MB
    unsigned short* qbf = p; p += (size_t)2 * 2048 * 512;      // 4MB
    unsigned short* kbf = p; p += (size_t)2 * 4096 * 512;      // 8MB
    unsigned short* wtq = p; p += 512 * 512;
    unsigned short* wtk = p; p += 512 * 512;
    unsigned short* wtv = p; p += 512 * 512;
    int* cntb = (int*)p;                                        // 2 ints

    dim3 blk(256);
    prep<<<dim3(3266), blk, 0, stream>>>(q, k, Wq, Wk, Wv, mask,
                                         qbf, kbf, wtq, wtk, wtv, cntb);
    proj3<<<dim3(1280), blk, 0, stream>>>(qbf, kbf, wtq, wtk, wtv,
                                          bq, bk, bv, mask, qh, kh, vt);
    attn14<<<dim3(512), dim3(512), 0, stream>>>(qh, kh, vt, cntb, out);
}

// Round 21
// 113.588 us; speedup vs baseline: 1.4017x; 1.4017x over previous
//
#include <hip/hip_runtime.h>
#include <hip/hip_bf16.h>

// R21: attention K/V prefetch moved from registers to LDS (global_load_lds,
// double-buffered) — breaks the allocator's load-sinking serialization
// (R7/R9/R10/R11/R20: arch VGPRs always squeezed to 64; reg prefetch dies).
// Per-wave 32q x 32k, 8 waves (4kq x 2qg), block tile 64q x 128k, grid 512
// = 2 blocks/CU (LDS 64KB: K/V dbuf unioned with the epilogue buffers).
// K tile [128k][64w] XOR(row&7); V tile [64w][128k] XOR(row&15); reads
// inverse-swizzled (rule #21) — bytes identical to R20's verified loads.
// prep/proj unchanged from R16 (Q pre-scaled by log2e/8; masks folded).

typedef short  s16x8 __attribute__((ext_vector_type(8)));
typedef short  s16x4 __attribute__((ext_vector_type(4)));
typedef float  f32x4 __attribute__((ext_vector_type(4)));
typedef float  f32x16 __attribute__((ext_vector_type(16)));
typedef unsigned int u32;
typedef unsigned int u32x4 __attribute__((ext_vector_type(4)));

__device__ __forceinline__ unsigned short f2bf(float x) {
    return __builtin_bit_cast(unsigned short, __float2bfloat16(x));
}
__device__ __forceinline__ void gload16(const void* g, void* lds) {
    __builtin_amdgcn_global_load_lds(
        (const __attribute__((address_space(1))) unsigned int*)g,
        (__attribute__((address_space(3))) unsigned int*)lds, 16, 0, 0);
}
__device__ __forceinline__ u32 cvtpk(float lo, float hi) {
    u32 r;
    asm("v_cvt_pk_bf16_f32 %0, %1, %2" : "=v"(r) : "v"(lo), "v"(hi));
    return r;
}

// ---------------- prep: cast q,k; transpose/cast W; count masked keys ------
__global__ __launch_bounds__(256) void prep(
    const float* __restrict__ q, const float* __restrict__ k,
    const float* __restrict__ Wq, const float* __restrict__ Wk,
    const float* __restrict__ Wv, const int* __restrict__ mask,
    unsigned short* __restrict__ qbf, unsigned short* __restrict__ kbf,
    unsigned short* __restrict__ wtq, unsigned short* __restrict__ wtk,
    unsigned short* __restrict__ wtv, int* __restrict__ cntb)
{
    __shared__ float T[64][65];
    const int bid = blockIdx.x;
    const int tid = threadIdx.x;
    if (bid < 3072) {
        const float* src = bid < 1024 ? q : k;
        unsigned short* dst = bid < 1024 ? qbf : kbf;
        int i = (bid < 1024 ? bid : bid - 1024) * 256 + tid;
        float4 a = reinterpret_cast<const float4*>(src)[2 * i];
        float4 b = reinterpret_cast<const float4*>(src)[2 * i + 1];
        s16x8 o;
        o[0] = (short)f2bf(a.x); o[1] = (short)f2bf(a.y);
        o[2] = (short)f2bf(a.z); o[3] = (short)f2bf(a.w);
        o[4] = (short)f2bf(b.x); o[5] = (short)f2bf(b.y);
        o[6] = (short)f2bf(b.z); o[7] = (short)f2bf(b.w);
        reinterpret_cast<s16x8*>(dst)[i] = o;
    } else if (bid < 3264) {
        int t = bid - 3072;
        int z = t >> 6;
        int tt = t & 63;
        const float* W = z == 0 ? Wq : z == 1 ? Wk : Wv;
        unsigned short* D = z == 0 ? wtq : z == 1 ? wtk : wtv;
        const int k0 = (tt >> 3) * 64, n0 = (tt & 7) * 64;
        const int r = tid >> 2, cq = tid & 3;
        #pragma unroll
        for (int p = 0; p < 4; ++p) {
            int c = (cq + 4 * p) * 4;
            float4 v = *reinterpret_cast<const float4*>(
                &W[(size_t)(k0 + r) * 512 + n0 + c]);
            T[c + 0][r] = v.x; T[c + 1][r] = v.y;
            T[c + 2][r] = v.z; T[c + 3][r] = v.w;
        }
        __syncthreads();
        #pragma unroll
        for (int p = 0; p < 4; ++p) {
            int kc = (cq + 4 * p) * 4;
            s16x4 o;
            o[0] = (short)f2bf(T[r][kc + 0]);
            o[1] = (short)f2bf(T[r][kc + 1]);
            o[2] = (short)f2bf(T[r][kc + 2]);
            o[3] = (short)f2bf(T[r][kc + 3]);
            *reinterpret_cast<s16x4*>(&D[(size_t)(n0 + r) * 512 + k0 + kc]) = o;
        }
    } else {
        // blocks 3264/3265: per-batch masked-key count (deterministic)
        __shared__ int red[4];
        int b = bid - 3264;
        int base = b * 4096 + tid * 16;
        int s = 0;
        #pragma unroll
        for (int p = 0; p < 4; ++p) {
            int4 m = *reinterpret_cast<const int4*>(&mask[base + 4 * p]);
            s += m.x + m.y + m.z + m.w;
        }
        #pragma unroll
        for (int off = 1; off < 64; off <<= 1)
            s += __shfl_xor(s, off);
        if ((tid & 63) == 0) red[tid >> 6] = s;
        __syncthreads();
        if (tid == 0)
            cntb[b] = 4096 - (red[0] + red[1] + red[2] + red[3]);
    }
}

// ---------------- fused 3-way projection GEMM, bf16 MFMA, 2-phase ----------
// mflag: 0 = Q (scale by log2e/8), 1 = K (zero masked rows), 2 = V^T.
__global__ __launch_bounds__(256) void proj3(
    const unsigned short* __restrict__ qbf, const unsigned short* __restrict__ kbf,
    const unsigned short* __restrict__ wtq, const unsigned short* __restrict__ wtk,
    const unsigned short* __restrict__ wtv,
    const float* __restrict__ bq, const float* __restrict__ bk,
    const float* __restrict__ bv, const int* __restrict__ mask,
    unsigned short* __restrict__ qh, unsigned short* __restrict__ kh,
    unsigned short* __restrict__ vt)
{
    __shared__ unsigned short As[2][128 * 64];
    __shared__ unsigned short Bs[2][64 * 64];

    const int tid  = threadIdx.x;
    const int wv   = tid >> 6;
    const int lane = tid & 63;
    const int g    = lane >> 4;
    const int ln   = lane & 15;
    const int swz  = (ln & 7) << 3;

    const int id = blockIdx.x;
    const unsigned short *A, *Wt;
    const float* bias;
    unsigned short* dst;
    int S, trans, nb, mb, mflag;
    if (id < 256)      { A = qbf; Wt = wtq; bias = bq; dst = qh; S = 2048; trans = 0; mflag = 0; nb = id & 7;         mb = id >> 3; }
    else if (id < 768) { A = kbf; Wt = wtk; bias = bk; dst = kh; S = 4096; trans = 0; mflag = 1; nb = (id - 256) & 7; mb = (id - 256) >> 3; }
    else               { A = kbf; Wt = wtv; bias = bv; dst = vt; S = 4096; trans = 1; mflag = 2; nb = (id - 768) & 7; mb = (id - 768) >> 3; }
    const int m0 = mb * 128, n0 = nb * 64;
    const float scl = (mflag == 0) ? 0.18033688011112042f : 1.f;

    f32x4 acc[4][2];
    #pragma unroll
    for (int i = 0; i < 4; ++i)
        #pragma unroll
        for (int j = 0; j < 2; ++j) acc[i][j] = (f32x4)0.f;

    auto stage = [&](int bufn, int k0) {
        #pragma unroll
        for (int p = 0; p < 4; ++p) {
            int slot = p * 256 + tid;
            int row = slot >> 3, cb = slot & 7;
            int cbp = cb ^ (row & 7);
            gload16(&A[(size_t)(m0 + row) * 512 + k0 + cbp * 8], &As[bufn][slot * 8]);
        }
        #pragma unroll
        for (int p = 0; p < 2; ++p) {
            int slot = p * 256 + tid;
            int row = slot >> 3, cb = slot & 7;
            int cbp = cb ^ (row & 7);
            gload16(&Wt[(size_t)(n0 + row) * 512 + k0 + cbp * 8], &Bs[bufn][slot * 8]);
        }
    };

    stage(0, 0);
    __syncthreads();
    int buf = 0;
    for (int kk = 0; kk < 8; ++kk) {
        if (kk < 7) stage(buf ^ 1, (kk + 1) * 64);
        #pragma unroll
        for (int ks = 0; ks < 2; ++ks) {
            s16x8 fa[2], fb[4];
            #pragma unroll
            for (int mi = 0; mi < 2; ++mi)
                fa[mi] = *reinterpret_cast<const s16x8*>(
                    &As[buf][((wv * 32 + 16 * mi + ln) * 64 + ks * 32 + g * 8) ^ swz]);
            #pragma unroll
            for (int nj = 0; nj < 4; ++nj)
                fb[nj] = *reinterpret_cast<const s16x8*>(
                    &Bs[buf][((16 * nj + ln) * 64 + ks * 32 + g * 8) ^ swz]);
            if (!trans) {
                #pragma unroll
                for (int mi = 0; mi < 2; ++mi)
                    #pragma unroll
                    for (int nj = 0; nj < 4; ++nj)
                        acc[nj][mi] = __builtin_amdgcn_mfma_f32_16x16x32_bf16(
                            fa[mi], fb[nj], acc[nj][mi], 0, 0, 0);
            } else {
                #pragma unroll
                for (int nj = 0; nj < 4; ++nj)
                    #pragma unroll
                    for (int mi = 0; mi < 2; ++mi)
                        acc[nj][mi] = __builtin_amdgcn_mfma_f32_16x16x32_bf16(
                            fb[nj], fa[mi], acc[nj][mi], 0, 0, 0);
            }
        }
        __syncthreads();
        buf ^= 1;
    }

    const int h    = nb;
    const int bidx = m0 / S;
    const int s0   = m0 - bidx * S;

    if (!trans) {
        float bvv[4];
        #pragma unroll
        for (int nj = 0; nj < 4; ++nj) bvv[nj] = bias[n0 + 16 * nj + ln];
        unsigned short* base = dst + (size_t)(bidx * 8 + h) * S * 64;
        #pragma unroll
        for (int mi = 0; mi < 2; ++mi)
            #pragma unroll
            for (int r = 0; r < 4; ++r) {
                int s = s0 + wv * 32 + 16 * mi + 4 * g + r;
                float fm = (mflag == 1) ? (float)mask[bidx * 4096 + s] : 1.f;
                float fs = fm * scl;
                #pragma unroll
                for (int nj = 0; nj < 4; ++nj)
                    base[(size_t)s * 64 + 16 * nj + ln] =
                        f2bf((acc[nj][mi][r] + bvv[nj]) * fs);
            }
    } else {
        float fmc[2];
        #pragma unroll
        for (int mi = 0; mi < 2; ++mi)
            fmc[mi] = (float)mask[bidx * 4096 + s0 + wv * 32 + 16 * mi + ln];
        unsigned short* base = dst + (size_t)(bidx * 8 + h) * 64 * (size_t)S;
        #pragma unroll
        for (int nj = 0; nj < 4; ++nj)
            #pragma unroll
            for (int r = 0; r < 4; ++r) {
                int w = 16 * nj + 4 * g + r;
                float bw = bias[n0 + w];
                #pragma unroll
                for (int mi = 0; mi < 2; ++mi)
                    base[(size_t)w * S + s0 + wv * 32 + 16 * mi + ln] =
                        f2bf((acc[nj][mi][r] + bw) * fmc[mi]);
            }
    }
}

// -------- attention: LDS-staged K/V (gload_lds dbuf), 32q x 32k / wave -----
__global__ __launch_bounds__(512) void attn15(
    const unsigned short* __restrict__ qh,  // [B,8,2048,64] bf16 (pre-scaled)
    const unsigned short* __restrict__ kh,  // [B,8,4096,64] bf16 (masked rows 0)
    const unsigned short* __restrict__ vt,  // [B,8,64,4096] bf16 (masked cols 0)
    const int* __restrict__ cntb,           // [B] masked-key counts
    float* __restrict__ out)                // [B,2048,512]
{
    union ShMem {
        struct { unsigned short Ks[2][128 * 64]; unsigned short Vs[2][64 * 128]; } kv;
        struct { float Ored[2][4][32][36]; float lw[2][4][32]; } ep;
    };
    __shared__ ShMem sm;

    const int tid  = threadIdx.x;
    const int wid  = tid >> 6;
    const int kq   = wid & 3;       // key-quarter of the 128-key tile
    const int qg   = wid >> 2;      // q-half (32 rows each) of the 64-row block
    const int lane = tid & 63;
    const int l31  = lane & 31;
    const int h32  = lane >> 5;

    const int id  = blockIdx.x;
    const int xcd = id & 7;
    const int j   = id >> 3;               // 0..63
    const int bh  = xcd * 2 + (j >> 5);
    const int qt  = j & 31;                // 64-row q tile
    const int b   = bh >> 3;
    const int hh  = bh & 7;

    const unsigned short* Kg = kh + (size_t)bh * 4096 * 64;
    const unsigned short* Vg = vt + (size_t)bh * 64 * 4096;

    s16x8 Qf[4];
    {
        const unsigned short* Qb = qh + ((size_t)bh * 2048 + qt * 64 + qg * 32) * 64;
        #pragma unroll
        for (int ks = 0; ks < 4; ++ks)
            Qf[ks] = *reinterpret_cast<const s16x8*>(
                &Qb[(size_t)l31 * 64 + ks * 16 + h32 * 8]);
    }

    f32x16 O[2];
    O[0] = (f32x16)0.f; O[1] = (f32x16)0.f;
    float l_acc = 0.f;

    // stage one 128-key tile: K [128][64] swz(row&7), V [64][128] swz(row&15)
    auto stage = [&](int bufn, int kt) {
        #pragma unroll
        for (int p = 0; p < 2; ++p) {
            int slot = p * 512 + tid;
            int row = slot >> 3, cb = slot & 7;
            int cbp = cb ^ (row & 7);
            gload16(&Kg[(size_t)(kt + row) * 64 + cbp * 8], &sm.kv.Ks[bufn][slot * 8]);
        }
        #pragma unroll
        for (int p = 0; p < 2; ++p) {
            int slot = p * 512 + tid;
            int row = slot >> 4, cg = slot & 15;
            int cgp = cg ^ (row & 15);
            gload16(&Vg[(size_t)row * 4096 + kt + cgp * 8], &sm.kv.Vs[bufn][slot * 8]);
        }
    };

    stage(0, 0);
    __syncthreads();
    int buf = 0;

    const int krow = kq * 32 + l31;            // this lane's K row in the tile
    const int kswz = (krow & 7) << 3;          // *8 elems
    const int vsw0 = (l31 & 15);               // V row & 15 (row = wt*32+l31)

    for (int t = 0; t < 32; ++t) {
        if (t < 31) stage(buf ^ 1, (t + 1) * 128);

        // ---- kf from LDS; QK^T: S^T[32 keys][32 q] ---------------------
        s16x8 kf[4];
        #pragma unroll
        for (int ks = 0; ks < 4; ++ks)
            kf[ks] = *reinterpret_cast<const s16x8*>(
                &sm.kv.Ks[buf][krow * 64 + (((2 * ks + h32) << 3) ^ kswz)]);
        f32x16 S = (f32x16)0.f;
        __builtin_amdgcn_s_setprio(1);
        #pragma unroll
        for (int ks = 0; ks < 4; ++ks)
            S = __builtin_amdgcn_mfma_f32_32x32x16_bf16(kf[ks], Qf[ks], S, 0, 0, 0);
        __builtin_amdgcn_s_setprio(0);

        // ---- no-max softmax: pp = exp2(S) ------------------------------
        float pp[16];
        #pragma unroll
        for (int r = 0; r < 16; ++r)
            pp[r] = exp2f(S[r]);
        l_acc += (((pp[0] + pp[1]) + (pp[2] + pp[3]))
                + ((pp[4] + pp[5]) + (pp[6] + pp[7])))
               + (((pp[8] + pp[9]) + (pp[10] + pp[11]))
                + ((pp[12] + pp[13]) + (pp[14] + pp[15])));
        u32 W[8];
        #pragma unroll
        for (int c = 0; c < 4; ++c) {
            W[2 * c + 0] = cvtpk(pp[4 * c + 0], pp[4 * c + 1]);
            W[2 * c + 1] = cvtpk(pp[4 * c + 2], pp[4 * c + 3]);
        }
        asm("v_permlane32_swap_b32 %0, %1" : "+v"(W[0]), "+v"(W[2]));
        asm("v_permlane32_swap_b32 %0, %1" : "+v"(W[1]), "+v"(W[3]));
        asm("v_permlane32_swap_b32 %0, %1" : "+v"(W[4]), "+v"(W[6]));
        asm("v_permlane32_swap_b32 %0, %1" : "+v"(W[5]), "+v"(W[7]));
        s16x8 pa[2];
        {
            u32x4 lo, hi;
            lo[0] = W[0]; lo[1] = W[1]; lo[2] = W[2]; lo[3] = W[3];
            hi[0] = W[4]; hi[1] = W[5]; hi[2] = W[6]; hi[3] = W[7];
            pa[0] = __builtin_bit_cast(s16x8, lo);
            pa[1] = __builtin_bit_cast(s16x8, hi);
        }

        // ---- vf from LDS; PV: O[q][w] += P x V -------------------------
        __builtin_amdgcn_s_setprio(1);
        #pragma unroll
        for (int wt = 0; wt < 2; ++wt) {
            int vrow = wt * 32 + l31;
            #pragma unroll
            for (int t2 = 0; t2 < 2; ++t2) {
                s16x8 vf = *reinterpret_cast<const s16x8*>(
                    &sm.kv.Vs[buf][vrow * 128 +
                        (((4 * kq + 2 * t2 + h32) ^ (vrow & 15)) << 3)]);
                O[wt] = __builtin_amdgcn_mfma_f32_32x32x16_bf16(
                    pa[t2], vf, O[wt], 0, 0, 0);
            }
        }
        __builtin_amdgcn_s_setprio(0);

        __syncthreads();
        buf ^= 1;
    }

    // ---- epilogue (LDS union reused after final barrier) ----------------
    float ls = l_acc + __shfl_xor(l_acc, 32);
    __syncthreads();                 // all K/V reads done; union safe
    if (lane < 32) sm.ep.lw[qg][kq][l31] = ls;

    const float cnt = (float)cntb[b];
    const int grp = tid >> 8;
    const int tt  = tid & 255;
    const int qr  = tt >> 3;
    const int w8  = (tt & 7) * 4;
    #pragma unroll
    for (int wt = 0; wt < 2; ++wt) {
        __syncthreads();
        #pragma unroll
        for (int r = 0; r < 16; ++r)
            sm.ep.Ored[qg][kq][(r & 3) + 8 * (r >> 2) + 4 * h32][l31] = O[wt][r];
        __syncthreads();
        float4 s0 = *reinterpret_cast<const float4*>(&sm.ep.Ored[grp][0][qr][w8]);
        float4 s1 = *reinterpret_cast<const float4*>(&sm.ep.Ored[grp][1][qr][w8]);
        float4 s2 = *reinterpret_cast<const float4*>(&sm.ep.Ored[grp][2][qr][w8]);
        float4 s3 = *reinterpret_cast<const float4*>(&sm.ep.Ored[grp][3][qr][w8]);
        float l = (sm.ep.lw[grp][0][qr] + sm.ep.lw[grp][1][qr]
                 + sm.ep.lw[grp][2][qr] + sm.ep.lw[grp][3][qr]) - cnt;
        float inv = 1.f / l;
        int qglob = qt * 64 + grp * 32 + qr;
        float4 o;
        o.x = (s0.x + s1.x + s2.x + s3.x) * inv;
        o.y = (s0.y + s1.y + s2.y + s3.y) * inv;
        o.z = (s0.z + s1.z + s2.z + s3.z) * inv;
        o.w = (s0.w + s1.w + s2.w + s3.w) * inv;
        *reinterpret_cast<float4*>(
            &out[((size_t)b * 2048 + qglob) * 512 + hh * 64 + wt * 32 + w8]) = o;
    }
}

extern "C" void kernel_launch(void* const* d_in, const int* in_sizes, int n_in,
                              void* d_out, int out_size, void* d_ws, size_t ws_size,
                              hipStream_t stream)
{
    const float* q    = (const float*)d_in[0];
    const float* k    = (const float*)d_in[1];
    const int*   mask = (const int*)  d_in[2];
    const float* Wq   = (const float*)d_in[3];
    const float* bq   = (const float*)d_in[4];
    const float* Wk   = (const float*)d_in[5];
    const float* bk   = (const float*)d_in[6];
    const float* Wv   = (const float*)d_in[7];
    const float* bv   = (const float*)d_in[8];
    float* out = (float*)d_out;

    // no aliasing: every buffer has a private range (total ~33.5MB)
    unsigned short* p = (unsigned short*)d_ws;
    unsigned short* qh  = p; p += (size_t)2 * 8 * 2048 * 64;   // 4MB
    unsigned short* kh  = p; p += (size_t)2 * 8 * 4096 * 64;   // 8MB
    unsigned short* vt  = p; p += (size_t)2 * 8 * 4096 * 64;   // 8MB
    unsigned short* qbf = p; p += (size_t)2 * 2048 * 512;      // 4MB
    unsigned short* kbf = p; p += (size_t)2 * 4096 * 512;      // 8MB
    unsigned short* wtq = p; p += 512 * 512;
    unsigned short* wtk = p; p += 512 * 512;
    unsigned short* wtv = p; p += 512 * 512;
    int* cntb = (int*)p;                                        // 2 ints

    dim3 blk(256);
    prep<<<dim3(3266), blk, 0, stream>>>(q, k, Wq, Wk, Wv, mask,
                                         qbf, kbf, wtq, wtk, wtv, cntb);
    proj3<<<dim3(1280), blk, 0, stream>>>(qbf, kbf, wtq, wtk, wtv,
                                          bq, bk, bv, mask, qh, kh, vt);
    attn15<<<dim3(512), dim3(512), 0, stream>>>(qh, kh, vt, cntb, out);
}

// Round 22
// 97.699 us; speedup vs baseline: 1.6296x; 1.1626x over previous
//
#include <hip/hip_runtime.h>
#include <hip/hip_bf16.h>

// R22 = R16/R19 base (direct-load attn, 73.7us verified; R21's LDS staging
// reverted: zero reuse -> doubled traffic + 2.6e7 bank conflicts) with:
// (a) attn: l computed via MFMA with a ones B-operand (4 extra MFMA/tile on
//     the 81%-idle matrix pipe) instead of the 32-add VALU tree. Masked keys
//     contribute exactly 1.0 -> cnt correction stays exact.
// (b) proj: 128x128 tiles (4 waves, 16 frag/wave, 64KB LDS dbuf, grid 640)
//     -> 2x MFMA per staging barrier, half the B traffic per output.

typedef short  s16x8 __attribute__((ext_vector_type(8)));
typedef short  s16x4 __attribute__((ext_vector_type(4)));
typedef float  f32x4 __attribute__((ext_vector_type(4)));
typedef float  f32x16 __attribute__((ext_vector_type(16)));
typedef unsigned int u32;
typedef unsigned int u32x4 __attribute__((ext_vector_type(4)));

__device__ __forceinline__ unsigned short f2bf(float x) {
    return __builtin_bit_cast(unsigned short, __float2bfloat16(x));
}
__device__ __forceinline__ void gload16(const void* g, void* lds) {
    __builtin_amdgcn_global_load_lds(
        (const __attribute__((address_space(1))) unsigned int*)g,
        (__attribute__((address_space(3))) unsigned int*)lds, 16, 0, 0);
}
__device__ __forceinline__ u32 cvtpk(float lo, float hi) {
    u32 r;
    asm("v_cvt_pk_bf16_f32 %0, %1, %2" : "=v"(r) : "v"(lo), "v"(hi));
    return r;
}

// ---------------- prep: cast q,k; transpose/cast W; count masked keys ------
__global__ __launch_bounds__(256) void prep(
    const float* __restrict__ q, const float* __restrict__ k,
    const float* __restrict__ Wq, const float* __restrict__ Wk,
    const float* __restrict__ Wv, const int* __restrict__ mask,
    unsigned short* __restrict__ qbf, unsigned short* __restrict__ kbf,
    unsigned short* __restrict__ wtq, unsigned short* __restrict__ wtk,
    unsigned short* __restrict__ wtv, int* __restrict__ cntb)
{
    __shared__ float T[64][65];
    const int bid = blockIdx.x;
    const int tid = threadIdx.x;
    if (bid < 3072) {
        const float* src = bid < 1024 ? q : k;
        unsigned short* dst = bid < 1024 ? qbf : kbf;
        int i = (bid < 1024 ? bid : bid - 1024) * 256 + tid;
        float4 a = reinterpret_cast<const float4*>(src)[2 * i];
        float4 b = reinterpret_cast<const float4*>(src)[2 * i + 1];
        s16x8 o;
        o[0] = (short)f2bf(a.x); o[1] = (short)f2bf(a.y);
        o[2] = (short)f2bf(a.z); o[3] = (short)f2bf(a.w);
        o[4] = (short)f2bf(b.x); o[5] = (short)f2bf(b.y);
        o[6] = (short)f2bf(b.z); o[7] = (short)f2bf(b.w);
        reinterpret_cast<s16x8*>(dst)[i] = o;
    } else if (bid < 3264) {
        int t = bid - 3072;
        int z = t >> 6;
        int tt = t & 63;
        const float* W = z == 0 ? Wq : z == 1 ? Wk : Wv;
        unsigned short* D = z == 0 ? wtq : z == 1 ? wtk : wtv;
        const int k0 = (tt >> 3) * 64, n0 = (tt & 7) * 64;
        const int r = tid >> 2, cq = tid & 3;
        #pragma unroll
        for (int p = 0; p < 4; ++p) {
            int c = (cq + 4 * p) * 4;
            float4 v = *reinterpret_cast<const float4*>(
                &W[(size_t)(k0 + r) * 512 + n0 + c]);
            T[c + 0][r] = v.x; T[c + 1][r] = v.y;
            T[c + 2][r] = v.z; T[c + 3][r] = v.w;
        }
        __syncthreads();
        #pragma unroll
        for (int p = 0; p < 4; ++p) {
            int kc = (cq + 4 * p) * 4;
            s16x4 o;
            o[0] = (short)f2bf(T[r][kc + 0]);
            o[1] = (short)f2bf(T[r][kc + 1]);
            o[2] = (short)f2bf(T[r][kc + 2]);
            o[3] = (short)f2bf(T[r][kc + 3]);
            *reinterpret_cast<s16x4*>(&D[(size_t)(n0 + r) * 512 + k0 + kc]) = o;
        }
    } else {
        // blocks 3264/3265: per-batch masked-key count (deterministic)
        __shared__ int red[4];
        int b = bid - 3264;
        int base = b * 4096 + tid * 16;
        int s = 0;
        #pragma unroll
        for (int p = 0; p < 4; ++p) {
            int4 m = *reinterpret_cast<const int4*>(&mask[base + 4 * p]);
            s += m.x + m.y + m.z + m.w;
        }
        #pragma unroll
        for (int off = 1; off < 64; off <<= 1)
            s += __shfl_xor(s, off);
        if ((tid & 63) == 0) red[tid >> 6] = s;
        __syncthreads();
        if (tid == 0)
            cntb[b] = 4096 - (red[0] + red[1] + red[2] + red[3]);
    }
}

// ---------------- fused 3-way projection GEMM, 128x128 tiles ---------------
// mflag: 0 = Q (scale by log2e/8), 1 = K (zero masked rows), 2 = V^T.
__global__ __launch_bounds__(256) void proj4(
    const unsigned short* __restrict__ qbf, const unsigned short* __restrict__ kbf,
    const unsigned short* __restrict__ wtq, const unsigned short* __restrict__ wtk,
    const unsigned short* __restrict__ wtv,
    const float* __restrict__ bq, const float* __restrict__ bk,
    const float* __restrict__ bv, const int* __restrict__ mask,
    unsigned short* __restrict__ qh, unsigned short* __restrict__ kh,
    unsigned short* __restrict__ vt)
{
    __shared__ unsigned short As[2][128 * 64];
    __shared__ unsigned short Bs[2][128 * 64];

    const int tid  = threadIdx.x;
    const int wv   = tid >> 6;
    const int lane = tid & 63;
    const int g    = lane >> 4;
    const int ln   = lane & 15;
    const int swz  = (ln & 7) << 3;
    const int r0   = (wv >> 1) * 64;   // wave row quadrant
    const int c0   = (wv & 1) * 64;    // wave col quadrant

    const int id = blockIdx.x;
    const unsigned short *A, *Wt;
    const float* bias;
    unsigned short* dst;
    int S, trans, nb, mb, mflag;
    if (id < 128)      { A = qbf; Wt = wtq; bias = bq; dst = qh; S = 2048; trans = 0; mflag = 0; nb = id & 3;         mb = id >> 2; }
    else if (id < 384) { A = kbf; Wt = wtk; bias = bk; dst = kh; S = 4096; trans = 0; mflag = 1; nb = (id - 128) & 3; mb = (id - 128) >> 2; }
    else               { A = kbf; Wt = wtv; bias = bv; dst = vt; S = 4096; trans = 1; mflag = 2; nb = (id - 384) & 3; mb = (id - 384) >> 2; }
    const int m0 = mb * 128, n0 = nb * 128;
    const float scl = (mflag == 0) ? 0.18033688011112042f : 1.f;

    f32x4 acc[4][4];
    #pragma unroll
    for (int i = 0; i < 4; ++i)
        #pragma unroll
        for (int j = 0; j < 4; ++j) acc[i][j] = (f32x4)0.f;

    auto stage = [&](int bufn, int k0) {
        #pragma unroll
        for (int p = 0; p < 4; ++p) {
            int slot = p * 256 + tid;
            int row = slot >> 3, cb = slot & 7;
            int cbp = cb ^ (row & 7);
            gload16(&A[(size_t)(m0 + row) * 512 + k0 + cbp * 8], &As[bufn][slot * 8]);
        }
        #pragma unroll
        for (int p = 0; p < 4; ++p) {
            int slot = p * 256 + tid;
            int row = slot >> 3, cb = slot & 7;
            int cbp = cb ^ (row & 7);
            gload16(&Wt[(size_t)(n0 + row) * 512 + k0 + cbp * 8], &Bs[bufn][slot * 8]);
        }
    };

    stage(0, 0);
    __syncthreads();
    int buf = 0;
    for (int kk = 0; kk < 8; ++kk) {
        if (kk < 7) stage(buf ^ 1, (kk + 1) * 64);
        #pragma unroll
        for (int ks = 0; ks < 2; ++ks) {
            s16x8 fa[4], fb[4];
            #pragma unroll
            for (int mi = 0; mi < 4; ++mi)
                fa[mi] = *reinterpret_cast<const s16x8*>(
                    &As[buf][((r0 + 16 * mi + ln) * 64 + ks * 32 + g * 8) ^ swz]);
            #pragma unroll
            for (int nj = 0; nj < 4; ++nj)
                fb[nj] = *reinterpret_cast<const s16x8*>(
                    &Bs[buf][((c0 + 16 * nj + ln) * 64 + ks * 32 + g * 8) ^ swz]);
            if (!trans) {
                #pragma unroll
                for (int mi = 0; mi < 4; ++mi)
                    #pragma unroll
                    for (int nj = 0; nj < 4; ++nj)
                        acc[mi][nj] = __builtin_amdgcn_mfma_f32_16x16x32_bf16(
                            fa[mi], fb[nj], acc[mi][nj], 0, 0, 0);
            } else {
                #pragma unroll
                for (int mi = 0; mi < 4; ++mi)
                    #pragma unroll
                    for (int nj = 0; nj < 4; ++nj)
                        acc[mi][nj] = __builtin_amdgcn_mfma_f32_16x16x32_bf16(
                            fb[nj], fa[mi], acc[mi][nj], 0, 0, 0);
            }
        }
        __syncthreads();
        buf ^= 1;
    }

    const int head = nb * 2 + (c0 >> 6);
    const int bidx = m0 / S;
    const int s0   = m0 - bidx * S;

    if (!trans) {
        float bvv[4];
        #pragma unroll
        for (int nj = 0; nj < 4; ++nj) bvv[nj] = bias[n0 + c0 + 16 * nj + ln];
        unsigned short* base = dst + (size_t)(bidx * 8 + head) * S * 64;
        #pragma unroll
        for (int mi = 0; mi < 4; ++mi)
            #pragma unroll
            for (int r = 0; r < 4; ++r) {
                int s = s0 + r0 + 16 * mi + 4 * g + r;
                float fm = (mflag == 1) ? (float)mask[bidx * 4096 + s] : 1.f;
                float fs = fm * scl;
                #pragma unroll
                for (int nj = 0; nj < 4; ++nj)
                    base[(size_t)s * 64 + 16 * nj + ln] =
                        f2bf((acc[mi][nj][r] + bvv[nj]) * fs);
            }
    } else {
        float fmc[4];
        #pragma unroll
        for (int mi = 0; mi < 4; ++mi)
            fmc[mi] = (float)mask[bidx * 4096 + s0 + r0 + 16 * mi + ln];
        unsigned short* base = dst + (size_t)(bidx * 8 + head) * 64 * (size_t)S;
        #pragma unroll
        for (int nj = 0; nj < 4; ++nj)
            #pragma unroll
            for (int r = 0; r < 4; ++r) {
                int wl = 16 * nj + 4 * g + r;
                float bw = bias[n0 + c0 + wl];
                #pragma unroll
                for (int mi = 0; mi < 4; ++mi)
                    base[(size_t)wl * S + s0 + r0 + 16 * mi + ln] =
                        f2bf((acc[mi][nj][r] + bw) * fmc[mi]);
            }
    }
}

// ------- attention: R16 core + l-via-MFMA (ones B-operand) -----------------
__global__ __launch_bounds__(512) void attn16(
    const unsigned short* __restrict__ qh,  // [B,8,2048,64] bf16 (pre-scaled)
    const unsigned short* __restrict__ kh,  // [B,8,4096,64] bf16 (masked rows 0)
    const unsigned short* __restrict__ vt,  // [B,8,64,4096] bf16 (masked cols 0)
    const int* __restrict__ cntb,           // [B] masked-key counts
    float* __restrict__ out)                // [B,2048,512]
{
    __shared__ float Ored[2][4][32][36];
    __shared__ float lw[2][2][4][32];

    const int tid  = threadIdx.x;
    const int wid  = tid >> 6;
    const int kq   = wid & 3;
    const int qg   = wid >> 2;
    const int lane = tid & 63;
    const int l31  = lane & 31;
    const int h32  = lane >> 5;

    const int id  = blockIdx.x;
    const int xcd = id & 7;
    const int j   = id >> 3;
    const int bh  = xcd * 2 + (j >> 4);
    const int qt  = j & 15;
    const int b   = bh >> 3;
    const int hh  = bh & 7;

    const unsigned short* Kp = kh + (size_t)bh * 4096 * 64
                               + (size_t)(kq * 32 + l31) * 64 + h32 * 8;
    const unsigned short* Vp0 = vt + (size_t)bh * 64 * 4096
                               + (size_t)l31 * 4096 + kq * 32 + h32 * 8;

    s16x8 Qf[2][4];
    {
        const unsigned short* Qb = qh + ((size_t)bh * 2048 + qt * 128 + qg * 64) * 64;
        #pragma unroll
        for (int qt2 = 0; qt2 < 2; ++qt2)
            #pragma unroll
            for (int ks = 0; ks < 4; ++ks)
                Qf[qt2][ks] = *reinterpret_cast<const s16x8*>(
                    &Qb[(size_t)(qt2 * 32 + l31) * 64 + ks * 16 + h32 * 8]);
    }

    f32x16 O[2][2], Ol[2];
    #pragma unroll
    for (int i = 0; i < 2; ++i) {
        Ol[i] = (f32x16)0.f;
        #pragma unroll
        for (int jj = 0; jj < 2; ++jj) O[i][jj] = (f32x16)0.f;
    }

    s16x8 ones;
    #pragma unroll
    for (int i = 0; i < 8; ++i) ones[i] = (short)0x3F80;   // bf16 1.0

    s16x8 kf[4], vf[4];

    auto loadK = [&](int t) {
        #pragma unroll
        for (int ks = 0; ks < 4; ++ks)
            kf[ks] = *reinterpret_cast<const s16x8*>(Kp + (size_t)t * 8192 + ks * 16);
    };
    auto loadV = [&](int t) {
        #pragma unroll
        for (int wt = 0; wt < 2; ++wt)
            #pragma unroll
            for (int t2 = 0; t2 < 2; ++t2)
                vf[wt * 2 + t2] = *reinterpret_cast<const s16x8*>(
                    Vp0 + (size_t)wt * 32 * 4096 + t * 128 + t2 * 16);
    };

    loadK(0); loadV(0);

    for (int t = 0; t < 32; ++t) {
        // ---- QK^T: S^T[32 keys][64 q] (S pre-scaled via Q) -------------
        f32x16 S[2];
        S[0] = (f32x16)0.f; S[1] = (f32x16)0.f;
        __builtin_amdgcn_s_setprio(1);
        #pragma unroll
        for (int ks = 0; ks < 4; ++ks) {
            S[0] = __builtin_amdgcn_mfma_f32_32x32x16_bf16(kf[ks], Qf[0][ks], S[0], 0, 0, 0);
            S[1] = __builtin_amdgcn_mfma_f32_32x32x16_bf16(kf[ks], Qf[1][ks], S[1], 0, 0, 0);
        }
        __builtin_amdgcn_s_setprio(0);
        if (t < 31) loadK(t + 1);

        // ---- no-max softmax: pp = exp2(S); pack only (l via MFMA) ------
        s16x8 pa[2][2];
        #pragma unroll
        for (int qt2 = 0; qt2 < 2; ++qt2) {
            float pp[16];
            #pragma unroll
            for (int r = 0; r < 16; ++r)
                pp[r] = exp2f(S[qt2][r]);
            u32 W[8];
            #pragma unroll
            for (int c = 0; c < 4; ++c) {
                W[2 * c + 0] = cvtpk(pp[4 * c + 0], pp[4 * c + 1]);
                W[2 * c + 1] = cvtpk(pp[4 * c + 2], pp[4 * c + 3]);
            }
            asm("v_permlane32_swap_b32 %0, %1" : "+v"(W[0]), "+v"(W[2]));
            asm("v_permlane32_swap_b32 %0, %1" : "+v"(W[1]), "+v"(W[3]));
            asm("v_permlane32_swap_b32 %0, %1" : "+v"(W[4]), "+v"(W[6]));
            asm("v_permlane32_swap_b32 %0, %1" : "+v"(W[5]), "+v"(W[7]));
            u32x4 lo, hi;
            lo[0] = W[0]; lo[1] = W[1]; lo[2] = W[2]; lo[3] = W[3];
            hi[0] = W[4]; hi[1] = W[5]; hi[2] = W[6]; hi[3] = W[7];
            pa[qt2][0] = __builtin_bit_cast(s16x8, lo);
            pa[qt2][1] = __builtin_bit_cast(s16x8, hi);
        }

        // ---- PV + l: O += P x V ; Ol += P x 1 --------------------------
        __builtin_amdgcn_s_setprio(1);
        #pragma unroll
        for (int qt2 = 0; qt2 < 2; ++qt2) {
            #pragma unroll
            for (int wt = 0; wt < 2; ++wt)
                #pragma unroll
                for (int t2 = 0; t2 < 2; ++t2)
                    O[qt2][wt] = __builtin_amdgcn_mfma_f32_32x32x16_bf16(
                        pa[qt2][t2], vf[wt * 2 + t2], O[qt2][wt], 0, 0, 0);
            #pragma unroll
            for (int t2 = 0; t2 < 2; ++t2)
                Ol[qt2] = __builtin_amdgcn_mfma_f32_32x32x16_bf16(
                    pa[qt2][t2], ones, Ol[qt2], 0, 0, 0);
        }
        __builtin_amdgcn_s_setprio(0);
        if (t < 31) loadV(t + 1);
    }

    // ---- l from Ol: rows (r&3)+8*(r>>2)+4*h32, cols redundant -----------
    if (l31 == 0) {
        #pragma unroll
        for (int qt2 = 0; qt2 < 2; ++qt2)
            #pragma unroll
            for (int r = 0; r < 16; ++r)
                lw[qg][qt2][kq][(r & 3) + 8 * (r >> 2) + 4 * h32] = Ol[qt2][r];
    }

    // ---- O reduction across the 4 kq waves; write final output ----------
    const float cnt = (float)cntb[b];
    const int grp = tid >> 8;
    const int tt  = tid & 255;
    const int qr  = tt >> 3;
    const int w8  = (tt & 7) * 4;
    #pragma unroll
    for (int qt2 = 0; qt2 < 2; ++qt2)
        #pragma unroll
        for (int wt = 0; wt < 2; ++wt) {
            __syncthreads();
            f32x16 oo = O[qt2][wt];
            #pragma unroll
            for (int r = 0; r < 16; ++r)
                Ored[qg][kq][(r & 3) + 8 * (r >> 2) + 4 * h32][l31] = oo[r];
            __syncthreads();
            float4 s  = *reinterpret_cast<const float4*>(&Ored[grp][0][qr][w8]);
            float4 s1 = *reinterpret_cast<const float4*>(&Ored[grp][1][qr][w8]);
            float4 s2 = *reinterpret_cast<const float4*>(&Ored[grp][2][qr][w8]);
            float4 s3 = *reinterpret_cast<const float4*>(&Ored[grp][3][qr][w8]);
            float l = (lw[grp][qt2][0][qr] + lw[grp][qt2][1][qr]
                     + lw[grp][qt2][2][qr] + lw[grp][qt2][3][qr]) - cnt;
            float inv = 1.f / l;
            int qglob = qt * 128 + grp * 64 + qt2 * 32 + qr;
            float4 o;
            o.x = (s.x + s1.x + s2.x + s3.x) * inv;
            o.y = (s.y + s1.y + s2.y + s3.y) * inv;
            o.z = (s.z + s1.z + s2.z + s3.z) * inv;
            o.w = (s.w + s1.w + s2.w + s3.w) * inv;
            *reinterpret_cast<float4*>(
                &out[((size_t)b * 2048 + qglob) * 512 + hh * 64 + wt * 32 + w8]) = o;
        }
}

extern "C" void kernel_launch(void* const* d_in, const int* in_sizes, int n_in,
                              void* d_out, int out_size, void* d_ws, size_t ws_size,
                              hipStream_t stream)
{
    const float* q    = (const float*)d_in[0];
    const float* k    = (const float*)d_in[1];
    const int*   mask = (const int*)  d_in[2];
    const float* Wq   = (const float*)d_in[3];
    const float* bq   = (const float*)d_in[4];
    const float* Wk   = (const float*)d_in[5];
    const float* bk   = (const float*)d_in[6];
    const float* Wv   = (const float*)d_in[7];
    const float* bv   = (const float*)d_in[8];
    float* out = (float*)d_out;

    // no aliasing: every buffer has a private range (total ~33.5MB)
    unsigned short* p = (unsigned short*)d_ws;
    unsigned short* qh  = p; p += (size_t)2 * 8 * 2048 * 64;   // 4MB
    unsigned short* kh  = p; p += (size_t)2 * 8 * 4096 * 64;   // 8MB
    unsigned short* vt  = p; p += (size_t)2 * 8 * 4096 * 64;   // 8MB
    unsigned short* qbf = p; p += (size_t)2 * 2048 * 512;      // 4MB
    unsigned short* kbf = p; p += (size_t)2 * 4096 * 512;      // 8MB
    unsigned short* wtq = p; p += 512 * 512;
    unsigned short* wtk = p; p += 512 * 512;
    unsigned short* wtv = p; p += 512 * 512;
    int* cntb = (int*)p;                                        // 2 ints

    dim3 blk(256);
    prep<<<dim3(3266), blk, 0, stream>>>(q, k, Wq, Wk, Wv, mask,
                                         qbf, kbf, wtq, wtk, wtv, cntb);
    proj4<<<dim3(640), blk, 0, stream>>>(qbf, kbf, wtq, wtk, wtv,
                                         bq, bk, bv, mask, qh, kh, vt);
    attn16<<<dim3(256), dim3(512), 0, stream>>>(qh, kh, vt, cntb, out);
}

// Round 23
// 95.743 us; speedup vs baseline: 1.6629x; 1.0204x over previous
//
#include <hip/hip_runtime.h>
#include <hip/hip_bf16.h>

// R23 = R22 with proj4's block-id mapping made nb-major XCD-clustered:
// local = nb*NMB + mb with NMB in {32,64} (both % 8 == 0), so the 4
// nb-sibling blocks sharing one 128-row A-panel land on the SAME XCD
// (id % 8 invariant) -> A-panel read once from HBM, 3x from that XCD's L2.
// attn16 (l via ones-MFMA, 74.0us) and prep unchanged from R22.

typedef short  s16x8 __attribute__((ext_vector_type(8)));
typedef short  s16x4 __attribute__((ext_vector_type(4)));
typedef float  f32x4 __attribute__((ext_vector_type(4)));
typedef float  f32x16 __attribute__((ext_vector_type(16)));
typedef unsigned int u32;
typedef unsigned int u32x4 __attribute__((ext_vector_type(4)));

__device__ __forceinline__ unsigned short f2bf(float x) {
    return __builtin_bit_cast(unsigned short, __float2bfloat16(x));
}
__device__ __forceinline__ void gload16(const void* g, void* lds) {
    __builtin_amdgcn_global_load_lds(
        (const __attribute__((address_space(1))) unsigned int*)g,
        (__attribute__((address_space(3))) unsigned int*)lds, 16, 0, 0);
}
__device__ __forceinline__ u32 cvtpk(float lo, float hi) {
    u32 r;
    asm("v_cvt_pk_bf16_f32 %0, %1, %2" : "=v"(r) : "v"(lo), "v"(hi));
    return r;
}

// ---------------- prep: cast q,k; transpose/cast W; count masked keys ------
__global__ __launch_bounds__(256) void prep(
    const float* __restrict__ q, const float* __restrict__ k,
    const float* __restrict__ Wq, const float* __restrict__ Wk,
    const float* __restrict__ Wv, const int* __restrict__ mask,
    unsigned short* __restrict__ qbf, unsigned short* __restrict__ kbf,
    unsigned short* __restrict__ wtq, unsigned short* __restrict__ wtk,
    unsigned short* __restrict__ wtv, int* __restrict__ cntb)
{
    __shared__ float T[64][65];
    const int bid = blockIdx.x;
    const int tid = threadIdx.x;
    if (bid < 3072) {
        const float* src = bid < 1024 ? q : k;
        unsigned short* dst = bid < 1024 ? qbf : kbf;
        int i = (bid < 1024 ? bid : bid - 1024) * 256 + tid;
        float4 a = reinterpret_cast<const float4*>(src)[2 * i];
        float4 b = reinterpret_cast<const float4*>(src)[2 * i + 1];
        s16x8 o;
        o[0] = (short)f2bf(a.x); o[1] = (short)f2bf(a.y);
        o[2] = (short)f2bf(a.z); o[3] = (short)f2bf(a.w);
        o[4] = (short)f2bf(b.x); o[5] = (short)f2bf(b.y);
        o[6] = (short)f2bf(b.z); o[7] = (short)f2bf(b.w);
        reinterpret_cast<s16x8*>(dst)[i] = o;
    } else if (bid < 3264) {
        int t = bid - 3072;
        int z = t >> 6;
        int tt = t & 63;
        const float* W = z == 0 ? Wq : z == 1 ? Wk : Wv;
        unsigned short* D = z == 0 ? wtq : z == 1 ? wtk : wtv;
        const int k0 = (tt >> 3) * 64, n0 = (tt & 7) * 64;
        const int r = tid >> 2, cq = tid & 3;
        #pragma unroll
        for (int p = 0; p < 4; ++p) {
            int c = (cq + 4 * p) * 4;
            float4 v = *reinterpret_cast<const float4*>(
                &W[(size_t)(k0 + r) * 512 + n0 + c]);
            T[c + 0][r] = v.x; T[c + 1][r] = v.y;
            T[c + 2][r] = v.z; T[c + 3][r] = v.w;
        }
        __syncthreads();
        #pragma unroll
        for (int p = 0; p < 4; ++p) {
            int kc = (cq + 4 * p) * 4;
            s16x4 o;
            o[0] = (short)f2bf(T[r][kc + 0]);
            o[1] = (short)f2bf(T[r][kc + 1]);
            o[2] = (short)f2bf(T[r][kc + 2]);
            o[3] = (short)f2bf(T[r][kc + 3]);
            *reinterpret_cast<s16x4*>(&D[(size_t)(n0 + r) * 512 + k0 + kc]) = o;
        }
    } else {
        // blocks 3264/3265: per-batch masked-key count (deterministic)
        __shared__ int red[4];
        int b = bid - 3264;
        int base = b * 4096 + tid * 16;
        int s = 0;
        #pragma unroll
        for (int p = 0; p < 4; ++p) {
            int4 m = *reinterpret_cast<const int4*>(&mask[base + 4 * p]);
            s += m.x + m.y + m.z + m.w;
        }
        #pragma unroll
        for (int off = 1; off < 64; off <<= 1)
            s += __shfl_xor(s, off);
        if ((tid & 63) == 0) red[tid >> 6] = s;
        __syncthreads();
        if (tid == 0)
            cntb[b] = 4096 - (red[0] + red[1] + red[2] + red[3]);
    }
}

// ---------------- fused 3-way projection GEMM, 128x128 tiles ---------------
// nb-major XCD-clustered ids: local = nb*NMB + mb (NMB % 8 == 0) -> the 4
// nb-siblings of an A-panel share an XCD -> A re-reads hit L2.
// mflag: 0 = Q (scale by log2e/8), 1 = K (zero masked rows), 2 = V^T.
__global__ __launch_bounds__(256) void proj4(
    const unsigned short* __restrict__ qbf, const unsigned short* __restrict__ kbf,
    const unsigned short* __restrict__ wtq, const unsigned short* __restrict__ wtk,
    const unsigned short* __restrict__ wtv,
    const float* __restrict__ bq, const float* __restrict__ bk,
    const float* __restrict__ bv, const int* __restrict__ mask,
    unsigned short* __restrict__ qh, unsigned short* __restrict__ kh,
    unsigned short* __restrict__ vt)
{
    __shared__ unsigned short As[2][128 * 64];
    __shared__ unsigned short Bs[2][128 * 64];

    const int tid  = threadIdx.x;
    const int wv   = tid >> 6;
    const int lane = tid & 63;
    const int g    = lane >> 4;
    const int ln   = lane & 15;
    const int swz  = (ln & 7) << 3;
    const int r0   = (wv >> 1) * 64;   // wave row quadrant
    const int c0   = (wv & 1) * 64;    // wave col quadrant

    const int id = blockIdx.x;
    const unsigned short *A, *Wt;
    const float* bias;
    unsigned short* dst;
    int S, trans, nb, mb, mflag;
    if (id < 128) {        // Q: NMB = 32
        int local = id;
        A = qbf; Wt = wtq; bias = bq; dst = qh; S = 2048; trans = 0; mflag = 0;
        nb = local >> 5; mb = local & 31;
    } else if (id < 384) { // K: NMB = 64
        int local = id - 128;
        A = kbf; Wt = wtk; bias = bk; dst = kh; S = 4096; trans = 0; mflag = 1;
        nb = local >> 6; mb = local & 63;
    } else {               // V: NMB = 64
        int local = id - 384;
        A = kbf; Wt = wtv; bias = bv; dst = vt; S = 4096; trans = 1; mflag = 2;
        nb = local >> 6; mb = local & 63;
    }
    const int m0 = mb * 128, n0 = nb * 128;
    const float scl = (mflag == 0) ? 0.18033688011112042f : 1.f;

    f32x4 acc[4][4];
    #pragma unroll
    for (int i = 0; i < 4; ++i)
        #pragma unroll
        for (int j = 0; j < 4; ++j) acc[i][j] = (f32x4)0.f;

    auto stage = [&](int bufn, int k0) {
        #pragma unroll
        for (int p = 0; p < 4; ++p) {
            int slot = p * 256 + tid;
            int row = slot >> 3, cb = slot & 7;
            int cbp = cb ^ (row & 7);
            gload16(&A[(size_t)(m0 + row) * 512 + k0 + cbp * 8], &As[bufn][slot * 8]);
        }
        #pragma unroll
        for (int p = 0; p < 4; ++p) {
            int slot = p * 256 + tid;
            int row = slot >> 3, cb = slot & 7;
            int cbp = cb ^ (row & 7);
            gload16(&Wt[(size_t)(n0 + row) * 512 + k0 + cbp * 8], &Bs[bufn][slot * 8]);
        }
    };

    stage(0, 0);
    __syncthreads();
    int buf = 0;
    for (int kk = 0; kk < 8; ++kk) {
        if (kk < 7) stage(buf ^ 1, (kk + 1) * 64);
        #pragma unroll
        for (int ks = 0; ks < 2; ++ks) {
            s16x8 fa[4], fb[4];
            #pragma unroll
            for (int mi = 0; mi < 4; ++mi)
                fa[mi] = *reinterpret_cast<const s16x8*>(
                    &As[buf][((r0 + 16 * mi + ln) * 64 + ks * 32 + g * 8) ^ swz]);
            #pragma unroll
            for (int nj = 0; nj < 4; ++nj)
                fb[nj] = *reinterpret_cast<const s16x8*>(
                    &Bs[buf][((c0 + 16 * nj + ln) * 64 + ks * 32 + g * 8) ^ swz]);
            if (!trans) {
                #pragma unroll
                for (int mi = 0; mi < 4; ++mi)
                    #pragma unroll
                    for (int nj = 0; nj < 4; ++nj)
                        acc[mi][nj] = __builtin_amdgcn_mfma_f32_16x16x32_bf16(
                            fa[mi], fb[nj], acc[mi][nj], 0, 0, 0);
            } else {
                #pragma unroll
                for (int mi = 0; mi < 4; ++mi)
                    #pragma unroll
                    for (int nj = 0; nj < 4; ++nj)
                        acc[mi][nj] = __builtin_amdgcn_mfma_f32_16x16x32_bf16(
                            fb[nj], fa[mi], acc[mi][nj], 0, 0, 0);
            }
        }
        __syncthreads();
        buf ^= 1;
    }

    const int head = nb * 2 + (c0 >> 6);
    const int bidx = m0 / S;
    const int s0   = m0 - bidx * S;

    if (!trans) {
        float bvv[4];
        #pragma unroll
        for (int nj = 0; nj < 4; ++nj) bvv[nj] = bias[n0 + c0 + 16 * nj + ln];
        unsigned short* base = dst + (size_t)(bidx * 8 + head) * S * 64;
        #pragma unroll
        for (int mi = 0; mi < 4; ++mi)
            #pragma unroll
            for (int r = 0; r < 4; ++r) {
                int s = s0 + r0 + 16 * mi + 4 * g + r;
                float fm = (mflag == 1) ? (float)mask[bidx * 4096 + s] : 1.f;
                float fs = fm * scl;
                #pragma unroll
                for (int nj = 0; nj < 4; ++nj)
                    base[(size_t)s * 64 + 16 * nj + ln] =
                        f2bf((acc[mi][nj][r] + bvv[nj]) * fs);
            }
    } else {
        float fmc[4];
        #pragma unroll
        for (int mi = 0; mi < 4; ++mi)
            fmc[mi] = (float)mask[bidx * 4096 + s0 + r0 + 16 * mi + ln];
        unsigned short* base = dst + (size_t)(bidx * 8 + head) * 64 * (size_t)S;
        #pragma unroll
        for (int nj = 0; nj < 4; ++nj)
            #pragma unroll
            for (int r = 0; r < 4; ++r) {
                int wl = 16 * nj + 4 * g + r;
                float bw = bias[n0 + c0 + wl];
                #pragma unroll
                for (int mi = 0; mi < 4; ++mi)
                    base[(size_t)wl * S + s0 + r0 + 16 * mi + ln] =
                        f2bf((acc[mi][nj][r] + bw) * fmc[mi]);
            }
    }
}

// ------- attention: R16 core + l-via-MFMA (ones B-operand) -----------------
__global__ __launch_bounds__(512) void attn16(
    const unsigned short* __restrict__ qh,  // [B,8,2048,64] bf16 (pre-scaled)
    const unsigned short* __restrict__ kh,  // [B,8,4096,64] bf16 (masked rows 0)
    const unsigned short* __restrict__ vt,  // [B,8,64,4096] bf16 (masked cols 0)
    const int* __restrict__ cntb,           // [B] masked-key counts
    float* __restrict__ out)                // [B,2048,512]
{
    __shared__ float Ored[2][4][32][36];
    __shared__ float lw[2][2][4][32];

    const int tid  = threadIdx.x;
    const int wid  = tid >> 6;
    const int kq   = wid & 3;
    const int qg   = wid >> 2;
    const int lane = tid & 63;
    const int l31  = lane & 31;
    const int h32  = lane >> 5;

    const int id  = blockIdx.x;
    const int xcd = id & 7;
    const int j   = id >> 3;
    const int bh  = xcd * 2 + (j >> 4);
    const int qt  = j & 15;
    const int b   = bh >> 3;
    const int hh  = bh & 7;

    const unsigned short* Kp = kh + (size_t)bh * 4096 * 64
                               + (size_t)(kq * 32 + l31) * 64 + h32 * 8;
    const unsigned short* Vp0 = vt + (size_t)bh * 64 * 4096
                               + (size_t)l31 * 4096 + kq * 32 + h32 * 8;

    s16x8 Qf[2][4];
    {
        const unsigned short* Qb = qh + ((size_t)bh * 2048 + qt * 128 + qg * 64) * 64;
        #pragma unroll
        for (int qt2 = 0; qt2 < 2; ++qt2)
            #pragma unroll
            for (int ks = 0; ks < 4; ++ks)
                Qf[qt2][ks] = *reinterpret_cast<const s16x8*>(
                    &Qb[(size_t)(qt2 * 32 + l31) * 64 + ks * 16 + h32 * 8]);
    }

    f32x16 O[2][2], Ol[2];
    #pragma unroll
    for (int i = 0; i < 2; ++i) {
        Ol[i] = (f32x16)0.f;
        #pragma unroll
        for (int jj = 0; jj < 2; ++jj) O[i][jj] = (f32x16)0.f;
    }

    s16x8 ones;
    #pragma unroll
    for (int i = 0; i < 8; ++i) ones[i] = (short)0x3F80;   // bf16 1.0

    s16x8 kf[4], vf[4];

    auto loadK = [&](int t) {
        #pragma unroll
        for (int ks = 0; ks < 4; ++ks)
            kf[ks] = *reinterpret_cast<const s16x8*>(Kp + (size_t)t * 8192 + ks * 16);
    };
    auto loadV = [&](int t) {
        #pragma unroll
        for (int wt = 0; wt < 2; ++wt)
            #pragma unroll
            for (int t2 = 0; t2 < 2; ++t2)
                vf[wt * 2 + t2] = *reinterpret_cast<const s16x8*>(
                    Vp0 + (size_t)wt * 32 * 4096 + t * 128 + t2 * 16);
    };

    loadK(0); loadV(0);

    for (int t = 0; t < 32; ++t) {
        // ---- QK^T: S^T[32 keys][64 q] (S pre-scaled via Q) -------------
        f32x16 S[2];
        S[0] = (f32x16)0.f; S[1] = (f32x16)0.f;
        __builtin_amdgcn_s_setprio(1);
        #pragma unroll
        for (int ks = 0; ks < 4; ++ks) {
            S[0] = __builtin_amdgcn_mfma_f32_32x32x16_bf16(kf[ks], Qf[0][ks], S[0], 0, 0, 0);
            S[1] = __builtin_amdgcn_mfma_f32_32x32x16_bf16(kf[ks], Qf[1][ks], S[1], 0, 0, 0);
        }
        __builtin_amdgcn_s_setprio(0);
        if (t < 31) loadK(t + 1);

        // ---- no-max softmax: pp = exp2(S); pack only (l via MFMA) ------
        s16x8 pa[2][2];
        #pragma unroll
        for (int qt2 = 0; qt2 < 2; ++qt2) {
            float pp[16];
            #pragma unroll
            for (int r = 0; r < 16; ++r)
                pp[r] = exp2f(S[qt2][r]);
            u32 W[8];
            #pragma unroll
            for (int c = 0; c < 4; ++c) {
                W[2 * c + 0] = cvtpk(pp[4 * c + 0], pp[4 * c + 1]);
                W[2 * c + 1] = cvtpk(pp[4 * c + 2], pp[4 * c + 3]);
            }
            asm("v_permlane32_swap_b32 %0, %1" : "+v"(W[0]), "+v"(W[2]));
            asm("v_permlane32_swap_b32 %0, %1" : "+v"(W[1]), "+v"(W[3]));
            asm("v_permlane32_swap_b32 %0, %1" : "+v"(W[4]), "+v"(W[6]));
            asm("v_permlane32_swap_b32 %0, %1" : "+v"(W[5]), "+v"(W[7]));
            u32x4 lo, hi;
            lo[0] = W[0]; lo[1] = W[1]; lo[2] = W[2]; lo[3] = W[3];
            hi[0] = W[4]; hi[1] = W[5]; hi[2] = W[6]; hi[3] = W[7];
            pa[qt2][0] = __builtin_bit_cast(s16x8, lo);
            pa[qt2][1] = __builtin_bit_cast(s16x8, hi);
        }

        // ---- PV + l: O += P x V ; Ol += P x 1 --------------------------
        __builtin_amdgcn_s_setprio(1);
        #pragma unroll
        for (int qt2 = 0; qt2 < 2; ++qt2) {
            #pragma unroll
            for (int wt = 0; wt < 2; ++wt)
                #pragma unroll
                for (int t2 = 0; t2 < 2; ++t2)
                    O[qt2][wt] = __builtin_amdgcn_mfma_f32_32x32x16_bf16(
                        pa[qt2][t2], vf[wt * 2 + t2], O[qt2][wt], 0, 0, 0);
            #pragma unroll
            for (int t2 = 0; t2 < 2; ++t2)
                Ol[qt2] = __builtin_amdgcn_mfma_f32_32x32x16_bf16(
                    pa[qt2][t2], ones, Ol[qt2], 0, 0, 0);
        }
        __builtin_amdgcn_s_setprio(0);
        if (t < 31) loadV(t + 1);
    }

    // ---- l from Ol: rows (r&3)+8*(r>>2)+4*h32, cols redundant -----------
    if (l31 == 0) {
        #pragma unroll
        for (int qt2 = 0; qt2 < 2; ++qt2)
            #pragma unroll
            for (int r = 0; r < 16; ++r)
                lw[qg][qt2][kq][(r & 3) + 8 * (r >> 2) + 4 * h32] = Ol[qt2][r];
    }

    // ---- O reduction across the 4 kq waves; write final output ----------
    const float cnt = (float)cntb[b];
    const int grp = tid >> 8;
    const int tt  = tid & 255;
    const int qr  = tt >> 3;
    const int w8  = (tt & 7) * 4;
    #pragma unroll
    for (int qt2 = 0; qt2 < 2; ++qt2)
        #pragma unroll
        for (int wt = 0; wt < 2; ++wt) {
            __syncthreads();
            f32x16 oo = O[qt2][wt];
            #pragma unroll
            for (int r = 0; r < 16; ++r)
                Ored[qg][kq][(r & 3) + 8 * (r >> 2) + 4 * h32][l31] = oo[r];
            __syncthreads();
            float4 s  = *reinterpret_cast<const float4*>(&Ored[grp][0][qr][w8]);
            float4 s1 = *reinterpret_cast<const float4*>(&Ored[grp][1][qr][w8]);
            float4 s2 = *reinterpret_cast<const float4*>(&Ored[grp][2][qr][w8]);
            float4 s3 = *reinterpret_cast<const float4*>(&Ored[grp][3][qr][w8]);
            float l = (lw[grp][qt2][0][qr] + lw[grp][qt2][1][qr]
                     + lw[grp][qt2][2][qr] + lw[grp][qt2][3][qr]) - cnt;
            float inv = 1.f / l;
            int qglob = qt * 128 + grp * 64 + qt2 * 32 + qr;
            float4 o;
            o.x = (s.x + s1.x + s2.x + s3.x) * inv;
            o.y = (s.y + s1.y + s2.y + s3.y) * inv;
            o.z = (s.z + s1.z + s2.z + s3.z) * inv;
            o.w = (s.w + s1.w + s2.w + s3.w) * inv;
            *reinterpret_cast<float4*>(
                &out[((size_t)b * 2048 + qglob) * 512 + hh * 64 + wt * 32 + w8]) = o;
        }
}

extern "C" void kernel_launch(void* const* d_in, const int* in_sizes, int n_in,
                              void* d_out, int out_size, void* d_ws, size_t ws_size,
                              hipStream_t stream)
{
    const float* q    = (const float*)d_in[0];
    const float* k    = (const float*)d_in[1];
    const int*   mask = (const int*)  d_in[2];
    const float* Wq   = (const float*)d_in[3];
    const float* bq   = (const float*)d_in[4];
    const float* Wk   = (const float*)d_in[5];
    const float* bk   = (const float*)d_in[6];
    const float* Wv   = (const float*)d_in[7];
    const float* bv   = (const float*)d_in[8];
    float* out = (float*)d_out;

    // no aliasing: every buffer has a private range (total ~33.5MB)
    unsigned short* p = (unsigned short*)d_ws;
    unsigned short* qh  = p; p += (size_t)2 * 8 * 2048 * 64;   // 4MB
    unsigned short* kh  = p; p += (size_t)2 * 8 * 4096 * 64;   // 8MB
    unsigned short* vt  = p; p += (size_t)2 * 8 * 4096 * 64;   // 8MB
    unsigned short* qbf = p; p += (size_t)2 * 2048 * 512;      // 4MB
    unsigned short* kbf = p; p += (size_t)2 * 4096 * 512;      // 8MB
    unsigned short* wtq = p; p += 512 * 512;
    unsigned short* wtk = p; p += 512 * 512;
    unsigned short* wtv = p; p += 512 * 512;
    int* cntb = (int*)p;                                        // 2 ints

    dim3 blk(256);
    prep<<<dim3(3266), blk, 0, stream>>>(q, k, Wq, Wk, Wv, mask,
                                         qbf, kbf, wtq, wtk, wtv, cntb);
    proj4<<<dim3(640), blk, 0, stream>>>(qbf, kbf, wtq, wtk, wtv,
                                         bq, bk, bv, mask, qh, kh, vt);
    attn16<<<dim3(256), dim3(512), 0, stream>>>(qh, kh, vt, cntb, out);
}